// Round 2
// baseline (223.151 us; speedup 1.0000x reference)
//
#include <hip/hip_runtime.h>
#include <math.h>

namespace {

constexpr int   kB     = 64;
constexpr int   kA     = 3;
constexpr int   kC     = 20;
constexpr int   kG     = 76;
constexpr int   kGG    = kG * kG;              // 5776
constexpr int   kCH    = 5 + kC;               // 25
constexpr int   kNCell = kB * kA * kGG;        // 1,108,992
constexpr int   kNC4   = kNCell / 4;           // 277,248
constexpr int   kBlockA = 256;
constexpr int   kGridA  = kNC4 / kBlockA;      // 1083 exact
constexpr int   kBlockB = 256;
constexpr int   kGridB  = 432;
constexpr float kEps   = 1e-7f;
constexpr float kInvG  = 1.0f / (float)kG;

// ws layout (32-bit words):
//  [0]      : uint  obj counter (== n_obj)
//  [1]      : float obj-conf sum
//  [2]      : float noobj-conf sum
//  [3]      : float coord (CIoU) sum
//  [4]      : float class sum
//  [16 ...] : int   compacted obj cell indices
constexpr int kListOff = 16;

__device__ __forceinline__ float softplus_fast(float x) {
  // log(1+exp(x)) via hw v_exp/v_log; arg of log in (1,2] -> accurate
  return fmaxf(x, 0.0f) + __logf(1.0f + __expf(-fabsf(x)));
}
__device__ __forceinline__ float sigmoidf(float x) {
  return 1.0f / (1.0f + __expf(-x));
}
__device__ __forceinline__ float clamp01(float x) {
  return fminf(fmaxf(x, 0.0f), 1.0f);
}

__device__ __forceinline__ void wave_reduce2(float& a, float& b) {
  #pragma unroll
  for (int off = 32; off > 0; off >>= 1) {
    a += __shfl_down(a, off, 64);
    b += __shfl_down(b, off, 64);
  }
}

__global__ __launch_bounds__(1) void init_ws(uint* ws_u) {
  ws_u[0] = 0u;
  ((float*)ws_u)[1] = 0.0f;
  ((float*)ws_u)[2] = 0.0f;
  ((float*)ws_u)[3] = 0.0f;
  ((float*)ws_u)[4] = 0.0f;
}

// Pass 1: stream targets (22 MB) + conf channel plane (4.4 MB).
// Conf BCE sums + wave-aggregated compaction of obj cell indices.
__global__ __launch_bounds__(kBlockA) void yolo_pass1(
    const float* __restrict__ preds,
    const float* __restrict__ tgts,
    uint* __restrict__ ws_u,
    int listCap) {
  const int q    = blockIdx.x * kBlockA + threadIdx.x;  // exact grid
  const int cell = q * 4;
  const int ba   = cell / kGG;
  const int j0   = cell - ba * kGG;

  // targets for 4 cells: 5 aligned float4
  const float4* tb = (const float4*)(tgts + (size_t)cell * 5);
  const float4 t0 = tb[0], t1 = tb[1], t2 = tb[2], t3 = tb[3], t4 = tb[4];
  (void)t0;
  const float conf[4] = { t1.x, t2.y, t3.z, t4.w };

  // conf channel (ch 4) for 4 cells
  const float* p4p = preds + (size_t)ba * kCH * kGG + (size_t)4 * kGG + j0;
  const float4 P4 = *(const float4*)p4p;
  const float p4a[4] = { P4.x, P4.y, P4.z, P4.w };

  float objc = 0.0f, noobj = 0.0f;
  int cnt = 0;
  int slot[4];

  #pragma unroll
  for (int i = 0; i < 4; ++i) {
    const bool obj = conf[i] > 0.0f;
    const float sp = softplus_fast(p4a[i]);
    if (obj) {
      objc += sp - p4a[i];   // softplus(-x) = softplus(x) - x  (t==1)
      slot[cnt++] = i;
    } else {
      noobj += sp;           // -log1p(-sigmoid(x)) = softplus(x)
    }
  }

  // wave-aggregated compaction: inclusive scan of cnt across 64 lanes
  const int lane = threadIdx.x & 63;
  int incl = cnt;
  #pragma unroll
  for (int off = 1; off < 64; off <<= 1) {
    const int n = __shfl_up(incl, off, 64);
    if (lane >= off) incl += n;
  }
  const int excl  = incl - cnt;
  const int total = __shfl(incl, 63, 64);
  int base = 0;
  if (lane == 63 && total > 0) base = atomicAdd(ws_u, (uint)total);
  base = __shfl(base, 63, 64);

  int* list = (int*)(ws_u + kListOff);
  for (int k = 0; k < cnt; ++k) {
    const int pos = base + excl + k;
    if (pos < listCap) list[pos] = cell + slot[k];
  }

  // reduce conf sums: wave reduce + one float atomic per wave
  wave_reduce2(objc, noobj);
  if (lane == 0) {
    float* ws_f = (float*)ws_u;
    atomicAdd(&ws_f[1], objc);
    atomicAdd(&ws_f[2], noobj);
  }
}

// Pass 2: obj cells only (~5%): CIoU + class loss. Grid-stride over list.
__global__ __launch_bounds__(kBlockB) void yolo_pass2(
    const float* __restrict__ preds,
    const float* __restrict__ tgts,
    const float* __restrict__ anchors,
    uint* __restrict__ ws_u,
    int listCap) {
  const int n = min((int)ws_u[0], listCap);
  const int* list = (const int*)(ws_u + kListOff);

  float coord = 0.0f, cls = 0.0f;

  for (int idx = blockIdx.x * kBlockB + threadIdx.x; idx < n;
       idx += gridDim.x * kBlockB) {
    const int cell = list[idx];
    const int ba   = cell / kGG;
    const int j    = cell - ba * kGG;
    const int a    = ba % kA;
    const int gy   = j / kG;
    const int gx   = j - gy * kG;
    const float fgx = (float)gx, fgy = (float)gy;

    const float aw = anchors[2 * a]     * kInvG;
    const float ah = anchors[2 * a + 1] * kInvG;

    const float* pb = preds + (size_t)ba * kCH * kGG + j;
    const float px = pb[0];
    const float py = pb[(size_t)1 * kGG];
    const float pwv = pb[(size_t)2 * kGG];
    const float phv = pb[(size_t)3 * kGG];

    const float* tc5 = tgts + (size_t)cell * 5;
    const float tx = tc5[0], ty = tc5[1], tw = tc5[2], th = tc5[3];

    // predicted box
    const float pcx = (fgx + sigmoidf(px)) * kInvG;
    const float pcy = (fgy + sigmoidf(py)) * kInvG;
    const float pw  = __expf(pwv) * aw;
    const float ph  = __expf(phv) * ah;
    const float x1p = clamp01(pcx - 0.5f * pw);
    const float y1p = clamp01(pcy - 0.5f * ph);
    const float x2p = clamp01(pcx + 0.5f * pw);
    const float y2p = clamp01(pcy + 0.5f * ph);

    // target box
    const float tcx = (fgx + tx) * kInvG;
    const float tcy = (fgy + ty) * kInvG;
    const float twv = __expf(tw) * aw;
    const float thv = __expf(th) * ah;
    const float x1t = clamp01(tcx - 0.5f * twv);
    const float y1t = clamp01(tcy - 0.5f * thv);
    const float x2t = clamp01(tcx + 0.5f * twv);
    const float y2t = clamp01(tcy + 0.5f * thv);

    // CIoU
    const float iw     = fmaxf(fminf(x2p, x2t) - fmaxf(x1p, x1t), 0.0f);
    const float ih     = fmaxf(fminf(y2p, y2t) - fmaxf(y1p, y1t), 0.0f);
    const float inter  = iw * ih;
    const float area_p = fmaxf(x2p - x1p, 0.0f) * fmaxf(y2p - y1p, 0.0f);
    const float area_t = fmaxf(x2t - x1t, 0.0f) * fmaxf(y2t - y1t, 0.0f);
    const float uni    = area_p + area_t - inter + kEps;
    const float iou    = inter / uni;
    const float dx     = (x1p + x2p - x1t - x2t) * 0.5f;
    const float dy     = (y1p + y2p - y1t - y2t) * 0.5f;
    const float rho2   = dx * dx + dy * dy;
    const float enw    = fmaxf(fmaxf(x2p, x2t) - fminf(x1p, x1t), kEps);
    const float enh    = fmaxf(fmaxf(y2p, y2t) - fminf(y1p, y1t), kEps);
    const float c2     = enw * enw + enh * enh;
    const float wp     = fmaxf(x2p - x1p, kEps);
    const float hp     = fmaxf(y2p - y1p, kEps);
    const float wt     = fmaxf(x2t - x1t, kEps);
    const float ht     = fmaxf(y2t - y1t, kEps);
    const float k4pi2  = 4.0f / (float)(M_PI * M_PI);
    const float dat    = atanf(wt / ht) - atanf(wp / hp);
    const float v      = k4pi2 * dat * dat;
    const float alpha  = v / (1.0f - iou + v + kEps);
    const float ciou   = iou - rho2 / (c2 + kEps) - alpha * v;
    coord += 1.0f - ciou;

    // class: -log(sigmoid(x)) = softplus(-x), 20 channels
    float cacc = 0.0f;
    #pragma unroll
    for (int c = 0; c < kC; ++c) {
      cacc += softplus_fast(-pb[(size_t)(5 + c) * kGG]);
    }
    cls += cacc;
  }

  wave_reduce2(coord, cls);
  if ((threadIdx.x & 63) == 0) {
    float* ws_f = (float*)ws_u;
    atomicAdd(&ws_f[3], coord);
    atomicAdd(&ws_f[4], cls);
  }
}

__global__ __launch_bounds__(1) void yolo_finish(
    const uint* __restrict__ ws_u, float* __restrict__ out) {
  const float* ws_f = (const float*)ws_u;
  const float n_obj   = (float)ws_u[0];
  const float objc    = ws_f[1];
  const float noobj   = ws_f[2];
  const float coord   = ws_f[3];
  const float cls     = ws_f[4];
  const float n_noobj = (float)kNCell - n_obj;

  const float coord_loss = (n_obj > 0.f)   ? coord / fmaxf(n_obj, 1.f)   : 0.f;
  const float obj_loss   = (n_obj > 0.f)   ? objc  / fmaxf(n_obj, 1.f)   : 0.f;
  const float noobj_loss = (n_noobj > 0.f) ? noobj / fmaxf(n_noobj, 1.f) : 0.f;
  const float class_loss = (n_obj > 0.f)   ? cls / fmaxf(n_obj * (float)kC, 1.f) : 0.f;

  out[0] = 10.0f * coord_loss + 1.0f * obj_loss + 0.5f * noobj_loss + class_loss;
}

}  // namespace

extern "C" void kernel_launch(void* const* d_in, const int* in_sizes, int n_in,
                              void* d_out, int out_size, void* d_ws, size_t ws_size,
                              hipStream_t stream) {
  const float* preds   = (const float*)d_in[0];
  const float* tgts    = (const float*)d_in[1];
  const float* anchors = (const float*)d_in[2];
  float* out = (float*)d_out;
  uint*  ws  = (uint*)d_ws;

  const int listCap = (int)(ws_size / 4) - kListOff;  // ints available for list

  init_ws<<<1, 1, 0, stream>>>(ws);
  yolo_pass1<<<kGridA, kBlockA, 0, stream>>>(preds, tgts, ws, listCap);
  yolo_pass2<<<kGridB, kBlockB, 0, stream>>>(preds, tgts, anchors, ws, listCap);
  yolo_finish<<<1, 1, 0, stream>>>(ws, out);
}

// Round 3
// 31.900 us; speedup vs baseline: 6.9954x; 6.9954x over previous
//
#include <hip/hip_runtime.h>
#include <math.h>

namespace {

constexpr int   kB     = 64;
constexpr int   kA     = 3;
constexpr int   kC     = 20;
constexpr int   kG     = 76;
constexpr int   kGG    = kG * kG;              // 5776
constexpr int   kCH    = 5 + kC;               // 25
constexpr int   kNCell = kB * kA * kGG;        // 1,108,992
constexpr int   kNC4   = kNCell / 4;           // 277,248
constexpr int   kBlockA = 256;
constexpr int   kGridA  = kNC4 / kBlockA;      // 1083 exact
constexpr int   kCellsPerBlk = kBlockA * 4;    // 1024
constexpr float kEps   = 1e-7f;
constexpr float kInvG  = 1.0f / (float)kG;

// ws layout (32-bit words), all per-block slots, ZERO global atomics:
//  counts   [0           .. kGridA)          int   true obj count per pass1 block
//  part1    [kGridA      .. kGridA*5)        float {objc, noobj, coord, cls} per pass1 block
//  part2    [kGridA*5    .. kGridA*7)        float {coord, cls} per pass2 block
//  lists    [kGridA*7    .. kGridA*7 + kGridA*cap)  int obj cell indices per block
constexpr int kPart1Off = kGridA;
constexpr int kPart2Off = kGridA * 5;
constexpr int kListOff  = kGridA * 7;

__device__ __forceinline__ float softplus_fast(float x) {
  // log(1+exp(x)) via hw v_exp/v_log; log argument in (1,2] -> accurate
  return fmaxf(x, 0.0f) + __logf(1.0f + __expf(-fabsf(x)));
}
__device__ __forceinline__ float sigmoidf(float x) {
  return 1.0f / (1.0f + __expf(-x));
}
__device__ __forceinline__ float clamp01(float x) {
  return fminf(fmaxf(x, 0.0f), 1.0f);
}

// Heavy per-obj-cell math: CIoU + 20-class BCE. Used by pass2 and the
// (practically never taken) pass1 overflow fallback.
__device__ __forceinline__ void heavy_cell(
    int cell, const float* __restrict__ preds, const float* __restrict__ tgts,
    const float* __restrict__ anchors, float& coord, float& cls) {
  const int ba = cell / kGG;
  const int j  = cell - ba * kGG;
  const int a  = ba % kA;
  const int gy = j / kG;
  const int gx = j - gy * kG;
  const float fgx = (float)gx, fgy = (float)gy;

  const float aw = anchors[2 * a]     * kInvG;
  const float ah = anchors[2 * a + 1] * kInvG;

  const float* pb = preds + (size_t)ba * kCH * kGG + j;
  const float px  = pb[0];
  const float py  = pb[(size_t)1 * kGG];
  const float pwv = pb[(size_t)2 * kGG];
  const float phv = pb[(size_t)3 * kGG];

  const float* tc5 = tgts + (size_t)cell * 5;
  const float tx = tc5[0], ty = tc5[1], tw = tc5[2], th = tc5[3];

  const float pcx = (fgx + sigmoidf(px)) * kInvG;
  const float pcy = (fgy + sigmoidf(py)) * kInvG;
  const float pw  = __expf(pwv) * aw;
  const float ph  = __expf(phv) * ah;
  const float x1p = clamp01(pcx - 0.5f * pw);
  const float y1p = clamp01(pcy - 0.5f * ph);
  const float x2p = clamp01(pcx + 0.5f * pw);
  const float y2p = clamp01(pcy + 0.5f * ph);

  const float tcx = (fgx + tx) * kInvG;
  const float tcy = (fgy + ty) * kInvG;
  const float twv = __expf(tw) * aw;
  const float thv = __expf(th) * ah;
  const float x1t = clamp01(tcx - 0.5f * twv);
  const float y1t = clamp01(tcy - 0.5f * thv);
  const float x2t = clamp01(tcx + 0.5f * twv);
  const float y2t = clamp01(tcy + 0.5f * thv);

  const float iw     = fmaxf(fminf(x2p, x2t) - fmaxf(x1p, x1t), 0.0f);
  const float ih     = fmaxf(fminf(y2p, y2t) - fmaxf(y1p, y1t), 0.0f);
  const float inter  = iw * ih;
  const float area_p = fmaxf(x2p - x1p, 0.0f) * fmaxf(y2p - y1p, 0.0f);
  const float area_t = fmaxf(x2t - x1t, 0.0f) * fmaxf(y2t - y1t, 0.0f);
  const float uni    = area_p + area_t - inter + kEps;
  const float iou    = inter / uni;
  const float dx     = (x1p + x2p - x1t - x2t) * 0.5f;
  const float dy     = (y1p + y2p - y1t - y2t) * 0.5f;
  const float rho2   = dx * dx + dy * dy;
  const float enw    = fmaxf(fmaxf(x2p, x2t) - fminf(x1p, x1t), kEps);
  const float enh    = fmaxf(fmaxf(y2p, y2t) - fminf(y1p, y1t), kEps);
  const float c2     = enw * enw + enh * enh;
  const float wp     = fmaxf(x2p - x1p, kEps);
  const float hp     = fmaxf(y2p - y1p, kEps);
  const float wt     = fmaxf(x2t - x1t, kEps);
  const float ht     = fmaxf(y2t - y1t, kEps);
  const float k4pi2  = 4.0f / (float)(M_PI * M_PI);
  const float dat    = atanf(wt / ht) - atanf(wp / hp);
  const float v      = k4pi2 * dat * dat;
  const float alpha  = v / (1.0f - iou + v + kEps);
  const float ciou   = iou - rho2 / (c2 + kEps) - alpha * v;
  coord += 1.0f - ciou;

  float cacc = 0.0f;
  #pragma unroll
  for (int c = 0; c < kC; ++c) {
    cacc += softplus_fast(-pb[(size_t)(5 + c) * kGG]);
  }
  cls += cacc;
}

// Deterministic block reduction of N floats; thread 0 writes to out[0..N).
template <int N, int BLK>
__device__ __forceinline__ void block_reduceN(float r[N], float* out) {
  #pragma unroll
  for (int off = 32; off > 0; off >>= 1) {
    #pragma unroll
    for (int s = 0; s < N; ++s) r[s] += __shfl_down(r[s], off, 64);
  }
  __shared__ float red[BLK / 64][N];
  const int lane = threadIdx.x & 63;
  const int wid  = threadIdx.x >> 6;
  if (lane == 0) {
    #pragma unroll
    for (int s = 0; s < N; ++s) red[wid][s] = r[s];
  }
  __syncthreads();
  if (threadIdx.x == 0) {
    #pragma unroll
    for (int s = 0; s < N; ++s) {
      float acc = red[0][s];
      #pragma unroll
      for (int w = 1; w < BLK / 64; ++w) acc += red[w][s];
      out[s] = acc;
    }
  }
}

// Pass 1: stream targets (22 MB) + conf plane (4.4 MB). Conf BCE partials +
// block-local deterministic compaction of obj cell indices. No atomics.
__global__ __launch_bounds__(kBlockA) void yolo_pass1(
    const float* __restrict__ preds,
    const float* __restrict__ tgts,
    const float* __restrict__ anchors,
    int* __restrict__ ws_i,
    int cap) {
  const int b    = blockIdx.x;
  const int q    = b * kBlockA + threadIdx.x;  // exact grid
  const int cell = q * 4;
  const int ba   = cell / kGG;
  const int j0   = cell - ba * kGG;

  // targets for 4 cells: 5 aligned float4; conf values are f[4],f[9],f[14],f[19]
  const float4* tb = (const float4*)(tgts + (size_t)cell * 5);
  const float4 t1 = tb[1], t2 = tb[2], t3 = tb[3], t4 = tb[4];
  const float conf[4] = { t1.x, t2.y, t3.z, t4.w };

  const float* p4p = preds + (size_t)ba * kCH * kGG + (size_t)4 * kGG + j0;
  const float4 P4 = *(const float4*)p4p;
  const float p4a[4] = { P4.x, P4.y, P4.z, P4.w };

  float r[4] = {0.f, 0.f, 0.f, 0.f};  // objc, noobj, coord(fallback), cls(fallback)
  unsigned msk = 0u;

  #pragma unroll
  for (int i = 0; i < 4; ++i) {
    const bool obj = conf[i] > 0.0f;
    const float sp = softplus_fast(p4a[i]);
    if (obj) {
      r[0] += sp - p4a[i];   // t==1: softplus(-x) = softplus(x) - x
      msk |= (1u << i);
    } else {
      r[1] += sp;            // -log1p(-sigmoid(x)) = softplus(x)
    }
  }
  const int cnt = __popc(msk);

  // deterministic block-wide exclusive position: wave scan + per-wave totals
  const int lane = threadIdx.x & 63;
  const int wid  = threadIdx.x >> 6;
  int incl = cnt;
  #pragma unroll
  for (int off = 1; off < 64; off <<= 1) {
    const int n = __shfl_up(incl, off, 64);
    if (lane >= off) incl += n;
  }
  const int excl = incl - cnt;

  __shared__ int wtot[kBlockA / 64];
  if (lane == 63) wtot[wid] = incl;
  __syncthreads();

  int wbase = 0;
  #pragma unroll
  for (int w = 0; w < kBlockA / 64; ++w) wbase += (w < wid) ? wtot[w] : 0;
  const int total = wtot[0] + wtot[1] + wtot[2] + wtot[3];

  if (threadIdx.x == 0) ws_i[b] = total;  // true obj count

  int* list = ws_i + kListOff + (size_t)b * cap;
  int p = wbase + excl;
  #pragma unroll
  for (int i = 0; i < 4; ++i) {
    if ((msk >> i) & 1u) {
      if (p < cap) {
        list[p] = cell + i;
      } else {
        // overflow fallback (practically never): do heavy math inline
        heavy_cell(cell + i, preds, tgts, anchors, r[2], r[3]);
      }
      ++p;
    }
  }

  block_reduceN<4, kBlockA>(r, (float*)(ws_i + kPart1Off) + (size_t)b * 4);
}

// Pass 2: one wave per pass1 block region; obj cells only (~51 per region,
// sorted -> good locality). No atomics.
__global__ __launch_bounds__(64) void yolo_pass2(
    const float* __restrict__ preds,
    const float* __restrict__ tgts,
    const float* __restrict__ anchors,
    int* __restrict__ ws_i,
    int cap) {
  const int b   = blockIdx.x;
  const int cnt = min(ws_i[b], cap);
  const int* list = ws_i + kListOff + (size_t)b * cap;

  float coord = 0.0f, cls = 0.0f;
  for (int i = threadIdx.x; i < cnt; i += 64) {
    heavy_cell(list[i], preds, tgts, anchors, coord, cls);
  }

  #pragma unroll
  for (int off = 32; off > 0; off >>= 1) {
    coord += __shfl_down(coord, off, 64);
    cls   += __shfl_down(cls,   off, 64);
  }
  if (threadIdx.x == 0) {
    float* p2 = (float*)(ws_i + kPart2Off) + (size_t)b * 2;
    p2[0] = coord;
    p2[1] = cls;
  }
}

__global__ __launch_bounds__(256) void yolo_finish(
    const int* __restrict__ ws_i, float* __restrict__ out) {
  const float* part1 = (const float*)(ws_i + kPart1Off);
  const float* part2 = (const float*)(ws_i + kPart2Off);

  float r[7] = {0.f, 0.f, 0.f, 0.f, 0.f, 0.f, 0.f};  // n, objc, noobj, coordA, clsA, coordB, clsB
  for (int i = threadIdx.x; i < kGridA; i += 256) {
    r[0] += (float)ws_i[i];
    r[1] += part1[(size_t)i * 4 + 0];
    r[2] += part1[(size_t)i * 4 + 1];
    r[3] += part1[(size_t)i * 4 + 2];
    r[4] += part1[(size_t)i * 4 + 3];
    r[5] += part2[(size_t)i * 2 + 0];
    r[6] += part2[(size_t)i * 2 + 1];
  }
  __shared__ float outbuf[7];
  block_reduceN<7, 256>(r, outbuf);
  __syncthreads();
  if (threadIdx.x == 0) {
    const float n_obj   = outbuf[0];
    const float objc    = outbuf[1];
    const float noobj   = outbuf[2];
    const float coord   = outbuf[3] + outbuf[5];
    const float cls     = outbuf[4] + outbuf[6];
    const float n_noobj = (float)kNCell - n_obj;

    const float coord_loss = (n_obj > 0.f)   ? coord / fmaxf(n_obj, 1.f)   : 0.f;
    const float obj_loss   = (n_obj > 0.f)   ? objc  / fmaxf(n_obj, 1.f)   : 0.f;
    const float noobj_loss = (n_noobj > 0.f) ? noobj / fmaxf(n_noobj, 1.f) : 0.f;
    const float class_loss = (n_obj > 0.f)   ? cls / fmaxf(n_obj * (float)kC, 1.f) : 0.f;

    out[0] = 10.0f * coord_loss + 1.0f * obj_loss + 0.5f * noobj_loss + class_loss;
  }
}

}  // namespace

extern "C" void kernel_launch(void* const* d_in, const int* in_sizes, int n_in,
                              void* d_out, int out_size, void* d_ws, size_t ws_size,
                              hipStream_t stream) {
  const float* preds   = (const float*)d_in[0];
  const float* tgts    = (const float*)d_in[1];
  const float* anchors = (const float*)d_in[2];
  float* out = (float*)d_out;
  int*   ws  = (int*)d_ws;

  // per-block list capacity from available workspace (max useful = 1024)
  long words = (long)(ws_size / 4) - kListOff;
  int cap = (int)(words / kGridA);
  if (cap > kCellsPerBlk) cap = kCellsPerBlk;
  if (cap < 0) cap = 0;

  yolo_pass1<<<kGridA, kBlockA, 0, stream>>>(preds, tgts, anchors, ws, cap);
  yolo_pass2<<<kGridA, 64, 0, stream>>>(preds, tgts, anchors, ws, cap);
  yolo_finish<<<1, 256, 0, stream>>>(ws, out);
}

// Round 4
// 27.048 us; speedup vs baseline: 8.2501x; 1.1794x over previous
//
#include <hip/hip_runtime.h>
#include <math.h>

namespace {

constexpr int   kB     = 64;
constexpr int   kA     = 3;
constexpr int   kC     = 20;
constexpr int   kG     = 76;
constexpr int   kGG    = kG * kG;              // 5776
constexpr int   kCH    = 5 + kC;               // 25
constexpr int   kNCell = kB * kA * kGG;        // 1,108,992
constexpr int   kNC4   = kNCell / 4;           // 277,248
constexpr int   kBlockA = 256;
constexpr int   kGridA  = kNC4 / kBlockA;      // 1083 exact
constexpr int   kCellsPerBlk = kBlockA * 4;    // 1024
constexpr float kEps   = 1e-7f;
constexpr float kInvG  = 1.0f / (float)kG;
constexpr float kPiO2  = 1.57079632679f;

// ws layout (32-bit words), no atomics anywhere:
//  counts [0        .. kGridA)      int   obj count per block
//  part   [kGridA   .. kGridA*5)    float {objc, noobj, coord, cls} per block
constexpr int kPartOff = kGridA;

__device__ __forceinline__ float softplus_fast(float x) {
  // log(1+exp(x)) via hw v_exp/v_log; log argument in (1,2] -> accurate
  return fmaxf(x, 0.0f) + __logf(1.0f + __expf(-fabsf(x)));
}
__device__ __forceinline__ float sigmoidf(float x) {
  return 1.0f / (1.0f + __expf(-x));
}
__device__ __forceinline__ float clamp01(float x) {
  return fminf(fmaxf(x, 0.0f), 1.0f);
}

// atan(num/den) for num,den > 0, via one fast divide + deg-9 minimax poly
// (|err| <= ~1e-5 on [0,1]); loss-level error << 0.159 threshold.
__device__ __forceinline__ float atan_ratio(float num, float den) {
  const float z  = __fdividef(fminf(num, den), fmaxf(num, den));
  const float z2 = z * z;
  float p = 0.0208351f;
  p = fmaf(p, z2, -0.0851330f);
  p = fmaf(p, z2,  0.1801410f);
  p = fmaf(p, z2, -0.3302995f);
  p = fmaf(p, z2,  0.9998660f);
  const float a = z * p;
  return (num > den) ? (kPiO2 - a) : a;
}

// Heavy per-obj-cell math: CIoU + 20-class BCE. Targets come from LDS.
__device__ __forceinline__ void heavy_cell(
    int cell, float tx, float ty, float tw, float th,
    const float* __restrict__ preds, const float* __restrict__ anchors,
    float& coord, float& cls) {
  const int ba = cell / kGG;
  const int j  = cell - ba * kGG;
  const int a  = ba % kA;
  const int gy = j / kG;
  const int gx = j - gy * kG;
  const float fgx = (float)gx, fgy = (float)gy;

  const float aw = anchors[2 * a]     * kInvG;
  const float ah = anchors[2 * a + 1] * kInvG;

  const float* pb = preds + (size_t)ba * kCH * kGG + j;
  const float px  = pb[0];
  const float py  = pb[(size_t)1 * kGG];
  const float pwv = pb[(size_t)2 * kGG];
  const float phv = pb[(size_t)3 * kGG];

  const float pcx = (fgx + sigmoidf(px)) * kInvG;
  const float pcy = (fgy + sigmoidf(py)) * kInvG;
  const float pw  = __expf(pwv) * aw;
  const float ph  = __expf(phv) * ah;
  const float x1p = clamp01(pcx - 0.5f * pw);
  const float y1p = clamp01(pcy - 0.5f * ph);
  const float x2p = clamp01(pcx + 0.5f * pw);
  const float y2p = clamp01(pcy + 0.5f * ph);

  const float tcx = (fgx + tx) * kInvG;
  const float tcy = (fgy + ty) * kInvG;
  const float twv = __expf(tw) * aw;
  const float thv = __expf(th) * ah;
  const float x1t = clamp01(tcx - 0.5f * twv);
  const float y1t = clamp01(tcy - 0.5f * thv);
  const float x2t = clamp01(tcx + 0.5f * twv);
  const float y2t = clamp01(tcy + 0.5f * thv);

  const float iw     = fmaxf(fminf(x2p, x2t) - fmaxf(x1p, x1t), 0.0f);
  const float ih     = fmaxf(fminf(y2p, y2t) - fmaxf(y1p, y1t), 0.0f);
  const float inter  = iw * ih;
  const float area_p = fmaxf(x2p - x1p, 0.0f) * fmaxf(y2p - y1p, 0.0f);
  const float area_t = fmaxf(x2t - x1t, 0.0f) * fmaxf(y2t - y1t, 0.0f);
  const float uni    = area_p + area_t - inter + kEps;
  const float iou    = __fdividef(inter, uni);
  const float dx     = (x1p + x2p - x1t - x2t) * 0.5f;
  const float dy     = (y1p + y2p - y1t - y2t) * 0.5f;
  const float rho2   = dx * dx + dy * dy;
  const float enw    = fmaxf(fmaxf(x2p, x2t) - fminf(x1p, x1t), kEps);
  const float enh    = fmaxf(fmaxf(y2p, y2t) - fminf(y1p, y1t), kEps);
  const float c2     = enw * enw + enh * enh;
  const float wp     = fmaxf(x2p - x1p, kEps);
  const float hp     = fmaxf(y2p - y1p, kEps);
  const float wt     = fmaxf(x2t - x1t, kEps);
  const float ht     = fmaxf(y2t - y1t, kEps);
  const float k4pi2  = 4.0f / (float)(M_PI * M_PI);
  const float dat    = atan_ratio(wt, ht) - atan_ratio(wp, hp);
  const float v      = k4pi2 * dat * dat;
  const float alpha  = __fdividef(v, 1.0f - iou + v + kEps);
  const float ciou   = iou - __fdividef(rho2, c2 + kEps) - alpha * v;
  coord += 1.0f - ciou;

  float cacc = 0.0f;
  #pragma unroll
  for (int c = 0; c < kC; ++c) {
    cacc += softplus_fast(-pb[(size_t)(5 + c) * kGG]);
  }
  cls += cacc;
}

// Deterministic block reduction of N floats; thread 0 writes to out[0..N).
template <int N, int BLK>
__device__ __forceinline__ void block_reduceN(float r[N], float* out) {
  #pragma unroll
  for (int off = 32; off > 0; off >>= 1) {
    #pragma unroll
    for (int s = 0; s < N; ++s) r[s] += __shfl_down(r[s], off, 64);
  }
  __shared__ float red[BLK / 64][N];
  const int lane = threadIdx.x & 63;
  const int wid  = threadIdx.x >> 6;
  if (lane == 0) {
    #pragma unroll
    for (int s = 0; s < N; ++s) red[wid][s] = r[s];
  }
  __syncthreads();
  if (threadIdx.x == 0) {
    #pragma unroll
    for (int s = 0; s < N; ++s) {
      float acc = red[0][s];
      #pragma unroll
      for (int w = 1; w < BLK / 64; ++w) acc += red[w][s];
      out[s] = acc;
    }
  }
}

// Fused kernel: stream targets+conf, compact obj cells into LDS, then the
// same block processes its obj cells densely (threads 0..total-1).
__global__ __launch_bounds__(kBlockA) void yolo_fused(
    const float* __restrict__ preds,
    const float* __restrict__ tgts,
    const float* __restrict__ anchors,
    int* __restrict__ ws_i) {
  __shared__ int    s_list[kCellsPerBlk];   // 4 KB
  __shared__ float4 s_tgt[kCellsPerBlk];    // 16 KB
  __shared__ int    s_wtot[kBlockA / 64];

  const int b    = blockIdx.x;
  const int q    = b * kBlockA + threadIdx.x;  // grid is exact
  const int cell = q * 4;
  const int ba   = cell / kGG;
  const int j0   = cell - ba * kGG;

  // targets for 4 cells: 5 aligned float4
  union { float4 v[5]; float f[20]; } T;
  const float4* tb = (const float4*)(tgts + (size_t)cell * 5);
  #pragma unroll
  for (int i = 0; i < 5; ++i) T.v[i] = tb[i];

  // conf channel (ch 4) for the 4 cells
  const float* p4p = preds + (size_t)ba * kCH * kGG + (size_t)4 * kGG + j0;
  const float4 P4 = *(const float4*)p4p;
  const float p4a[4] = { P4.x, P4.y, P4.z, P4.w };

  float r[4] = {0.f, 0.f, 0.f, 0.f};  // objc, noobj, coord, cls
  unsigned msk = 0u;

  #pragma unroll
  for (int i = 0; i < 4; ++i) {
    const bool obj = T.f[i * 5 + 4] > 0.0f;
    const float sp = softplus_fast(p4a[i]);
    if (obj) {
      r[0] += sp - p4a[i];   // t==1: softplus(-x) = softplus(x) - x
      msk |= (1u << i);
    } else {
      r[1] += sp;            // -log1p(-sigmoid(x)) = softplus(x)
    }
  }
  const int cnt = __popc(msk);

  // deterministic block-wide exclusive position: wave scan + per-wave totals
  const int lane = threadIdx.x & 63;
  const int wid  = threadIdx.x >> 6;
  int incl = cnt;
  #pragma unroll
  for (int off = 1; off < 64; off <<= 1) {
    const int n = __shfl_up(incl, off, 64);
    if (lane >= off) incl += n;
  }
  const int excl = incl - cnt;

  if (lane == 63) s_wtot[wid] = incl;
  __syncthreads();

  int wbase = 0;
  #pragma unroll
  for (int w = 0; w < kBlockA / 64; ++w) wbase += (w < wid) ? s_wtot[w] : 0;
  const int total = s_wtot[0] + s_wtot[1] + s_wtot[2] + s_wtot[3];

  if (threadIdx.x == 0) ws_i[b] = total;

  int p = wbase + excl;
  #pragma unroll
  for (int i = 0; i < 4; ++i) {
    if ((msk >> i) & 1u) {
      s_list[p] = cell + i;
      s_tgt[p]  = make_float4(T.f[i * 5 + 0], T.f[i * 5 + 1],
                              T.f[i * 5 + 2], T.f[i * 5 + 3]);
      ++p;
    }
  }
  __syncthreads();

  // dense heavy phase over this block's obj cells (total ~51 of 1024)
  for (int i = threadIdx.x; i < total; i += kBlockA) {
    const int c  = s_list[i];
    const float4 t4 = s_tgt[i];
    heavy_cell(c, t4.x, t4.y, t4.z, t4.w, preds, anchors, r[2], r[3]);
  }

  block_reduceN<4, kBlockA>(r, (float*)(ws_i + kPartOff) + (size_t)b * 4);
}

__global__ __launch_bounds__(256) void yolo_finish(
    const int* __restrict__ ws_i, float* __restrict__ out) {
  const float* part = (const float*)(ws_i + kPartOff);

  float r[5] = {0.f, 0.f, 0.f, 0.f, 0.f};  // n, objc, noobj, coord, cls
  for (int i = threadIdx.x; i < kGridA; i += 256) {
    r[0] += (float)ws_i[i];
    r[1] += part[(size_t)i * 4 + 0];
    r[2] += part[(size_t)i * 4 + 1];
    r[3] += part[(size_t)i * 4 + 2];
    r[4] += part[(size_t)i * 4 + 3];
  }
  __shared__ float outbuf[5];
  block_reduceN<5, 256>(r, outbuf);
  __syncthreads();
  if (threadIdx.x == 0) {
    const float n_obj   = outbuf[0];
    const float objc    = outbuf[1];
    const float noobj   = outbuf[2];
    const float coord   = outbuf[3];
    const float cls     = outbuf[4];
    const float n_noobj = (float)kNCell - n_obj;

    const float coord_loss = (n_obj > 0.f)   ? coord / fmaxf(n_obj, 1.f)   : 0.f;
    const float obj_loss   = (n_obj > 0.f)   ? objc  / fmaxf(n_obj, 1.f)   : 0.f;
    const float noobj_loss = (n_noobj > 0.f) ? noobj / fmaxf(n_noobj, 1.f) : 0.f;
    const float class_loss = (n_obj > 0.f)   ? cls / fmaxf(n_obj * (float)kC, 1.f) : 0.f;

    out[0] = 10.0f * coord_loss + 1.0f * obj_loss + 0.5f * noobj_loss + class_loss;
  }
}

}  // namespace

extern "C" void kernel_launch(void* const* d_in, const int* in_sizes, int n_in,
                              void* d_out, int out_size, void* d_ws, size_t ws_size,
                              hipStream_t stream) {
  const float* preds   = (const float*)d_in[0];
  const float* tgts    = (const float*)d_in[1];
  const float* anchors = (const float*)d_in[2];
  float* out = (float*)d_out;
  int*   ws  = (int*)d_ws;

  yolo_fused<<<kGridA, kBlockA, 0, stream>>>(preds, tgts, anchors, ws);
  yolo_finish<<<1, 256, 0, stream>>>(ws, out);
}